// Round 2
// baseline (334.515 us; speedup 1.0000x reference)
//
#include <hip/hip_runtime.h>
#include <hip/hip_bf16.h>
#include <stdint.h>

// ModulatedConv2d: N=16, IC=OC=256, H=W=64, K=3, STYLE=512.
// out = demod[n,oc] * conv2d( x * (1+s)[n,ic], weight )   (StyleGAN2 identity)
// Dtype of harness buffers detected on-device (fp32 vs bf16); compute is bf16 MFMA.

#define NB  16
#define IC  256
#define OC  256
#define HW  64
#define HWP 66
#define SD  512
#define SPATIAL 4096

typedef __hip_bfloat16 bf16;
typedef __bf16 bf16x8 __attribute__((ext_vector_type(8)));
typedef float  f32x4  __attribute__((ext_vector_type(4)));
typedef uint32_t u32a3 __attribute__((address_space(3)));
typedef const uint32_t u32a1 __attribute__((address_space(1)));

static __device__ __forceinline__ float bu2f(unsigned short u) {
    union { unsigned int i; float f; } c; c.i = ((unsigned int)u) << 16; return c.f;
}
static __device__ __forceinline__ float b2f(bf16 v) { return __bfloat162float(v); }
static __device__ __forceinline__ unsigned short f2bu(float f) {
    bf16 h = __float2bfloat16(f);
    union { bf16 b; unsigned short u; } c; c.b = h; return c.u;
}
static __device__ __forceinline__ void gll16(const void* g, void* l) {
    __builtin_amdgcn_global_load_lds((u32a1*)g, (u32a3*)l, 16, 0, 0);
}
// dtype-flexible scalar load: isf32 ? fp32 : bf16
static __device__ __forceinline__ float ldf(const void* p, size_t i, int isf32) {
    return isf32 ? ((const float*)p)[i] : b2f(((const bf16*)p)[i]);
}

// --- K0: detect buffer dtype. fp32 read as bf16 -> even halves have random
// exponents (huge/NaN ~37%); true bf16 N(0,1) never exceeds ~5. ---------------
__global__ void k_detect(const void* __restrict__ style, int* __restrict__ flag) {
    if (threadIdx.x == 0 && blockIdx.x == 0) {
        const unsigned short* u = (const unsigned short*)style;
        int cnt = 0;
        for (int i = 0; i < 128; ++i) {
            float v = bu2f(u[i]);
            if (!(fabsf(v) <= 1e10f)) cnt++;   // catches huge, Inf, NaN
        }
        flag[0] = (cnt >= 4) ? 1 : 0;          // 1 => fp32 buffers
    }
}

// --- K1: scale[n,ic] = 1 + style[n,:] . mod_w[ic,:] + mod_b[ic] -------------
__global__ void k_scale(const void* __restrict__ style, const void* __restrict__ mod_w,
                        const void* __restrict__ mod_b, const int* __restrict__ flag,
                        float* __restrict__ scale) {
    __shared__ float st[SD];
    int isf = flag[0];
    int n = blockIdx.x, t = threadIdx.x;
    st[t]       = ldf(style, (size_t)n * SD + t, isf);
    st[t + 256] = ldf(style, (size_t)n * SD + t + 256, isf);
    __syncthreads();
    float acc = 0.f;
    size_t mwb = (size_t)t * SD;
    for (int k = 0; k < SD; ++k) acc += ldf(mod_w, mwb + k, isf) * st[k];
    scale[n * IC + t] = acc + ldf(mod_b, t, isf) + 1.0f;
}

// --- K2: wsq[oc,ic] = sum_r weight[oc,ic,r]^2 -------------------------------
__global__ void k_wsq(const void* __restrict__ weight, const int* __restrict__ flag,
                      float* __restrict__ wsq) {
    int isf = flag[0];
    int tid = blockIdx.x * 256 + threadIdx.x;  // oc*256+ic
    size_t base = (size_t)tid * 9;
    float s = 0.f;
    #pragma unroll
    for (int r = 0; r < 9; ++r) { float v = ldf(weight, base + r, isf); s += v * v; }
    wsq[tid] = s;
}

// --- K3: demod[n,oc] = rsqrt( sum_ic wsq[oc,ic]*scale[n,ic]^2 + eps ) -------
__global__ void k_demod(const float* __restrict__ wsq, const float* __restrict__ scale,
                        float* __restrict__ demod) {
    __shared__ float sc[IC];
    int n = blockIdx.x, oc = threadIdx.x;
    sc[oc] = scale[n * IC + oc];
    __syncthreads();
    const float* wp = wsq + (size_t)oc * IC;
    float acc = 0.f;
    for (int ic = 0; ic < IC; ++ic) { float s = sc[ic]; acc += wp[ic] * s * s; }
    demod[n * OC + oc] = rsqrtf(acc + 1e-8f);
}

// --- K4: wt2[r][oc][ic] = bf16(weight[oc][ic][r])  (ic contiguous) ----------
__global__ void k_repack(const void* __restrict__ weight, const int* __restrict__ flag,
                         bf16* __restrict__ wt2) {
    int isf = flag[0];
    int tid = blockIdx.x * 256 + threadIdx.x;  // r*65536 + oc*256 + ic
    int ic = tid & 255, oc = (tid >> 8) & 255, r = tid >> 16;
    wt2[tid] = __float2bfloat16(ldf(weight, ((size_t)(oc * 256 + ic)) * 9 + r, isf));
}

// --- K5a: zero the padded NHWC buffer ---------------------------------------
__global__ void k_zero(uint4* __restrict__ p, int n4) {
    int i = blockIdx.x * 256 + threadIdx.x;
    if (i < n4) p[i] = make_uint4(0u, 0u, 0u, 0u);
}

// --- K5b: xs[n][1+y][1+x][ic] = bf16( x[n,ic,y,x] * scale[n,ic] ) -----------
__global__ void k_xs(const void* __restrict__ x, const int* __restrict__ flag,
                     const float* __restrict__ scale, bf16* __restrict__ xs) {
    __shared__ unsigned short tile[IC * (HW + 2)];
    int isf = flag[0];
    int y = blockIdx.x, n = blockIdx.y, t = threadIdx.x;
    const float* sc = scale + n * IC;
    size_t xbase = ((size_t)n * IC) * SPATIAL + (size_t)y * HW;
    #pragma unroll 4
    for (int i = 0; i < 64; ++i) {
        int idx = i * 256 + t;
        int icr = idx >> 6, sp = idx & 63;
        float v = ldf(x, xbase + (size_t)icr * SPATIAL + sp, isf) * sc[icr];
        tile[icr * (HW + 2) + sp] = f2bu(v);
    }
    __syncthreads();
    unsigned short* dst = reinterpret_cast<unsigned short*>(
        xs + (((size_t)n * HWP + (y + 1)) * HWP + 1) * IC);
    #pragma unroll 4
    for (int i = 0; i < 64; ++i) {
        dst[i * IC + t] = tile[t * (HW + 2) + i];  // sp=i, ic=t
    }
}

// --- K6: implicit-GEMM conv. 128 spatial x 128 oc per block, BK=32 ----------
__global__ __launch_bounds__(256)
void k_conv(const bf16* __restrict__ xs, const bf16* __restrict__ wt2,
            const float* __restrict__ demod, const int* __restrict__ flag,
            void* __restrict__ out) {
    __shared__ unsigned short Al[128 * 32];
    __shared__ unsigned short Bl[128 * 32];
    int isf = flag[0];
    int t = threadIdx.x;
    int l = t & 63, w = t >> 6;
    int wm = w & 1, wn = w >> 1;
    int bn = blockIdx.x;             // oc tile: 0..1
    int bm = blockIdx.y;             // spatial tile: 0..511
    int n = bm >> 5;
    int sp_base = (bm & 31) << 7;    // 128 positions = 2 image rows
    int oc_base = bn << 7;

    int lq = l >> 2, lc = l & 3;
    int p0 = w * 16 + lq;
    int y0 = (sp_base + p0) >> 6, x0 = (sp_base + p0) & 63;
    const bf16* gA0 = xs + (((size_t)n * HWP + y0) * HWP + x0) * IC + lc * 8;
    const bf16* gA1 = xs + (((size_t)n * HWP + (y0 + 1)) * HWP + x0) * IC + lc * 8;
    const bf16* gB0 = wt2 + ((size_t)(oc_base + w * 16 + lq)) * IC + lc * 8;
    const bf16* gB1 = gB0 + (size_t)64 * IC;
    char* Abase = (char*)Al + w * 1024;   // wave-uniform LDS dest
    char* Bbase = (char*)Bl + w * 1024;

    f32x4 acc[4][4];
    #pragma unroll
    for (int i = 0; i < 4; ++i)
        #pragma unroll
        for (int j = 0; j < 4; ++j) acc[i][j] = (f32x4){0.f, 0.f, 0.f, 0.f};

    int rowA = (wm * 64 + (l & 15)) * 32;
    int rowB = (wn * 64 + (l & 15)) * 32;
    int kq = (l >> 4) * 8;

    for (int ch = 0; ch < 72; ++ch) {
        int r = ch >> 3;
        int ic0 = (ch & 7) << 5;
        int ky = r / 3, kx = r - ky * 3;
        int aoff = (ky * HWP + kx) * IC + ic0;
        int boff = (r << 16) + ic0;
        __syncthreads();
        gll16(gA0 + aoff, Abase);
        gll16(gA1 + aoff, Abase + 4096);
        gll16(gB0 + boff, Bbase);
        gll16(gB1 + boff, Bbase + 4096);
        __syncthreads();
        bf16x8 af[4], bfr[4];
        #pragma unroll
        for (int mi = 0; mi < 4; ++mi)
            af[mi] = *reinterpret_cast<const bf16x8*>(&Al[rowA + mi * 512 + kq]);
        #pragma unroll
        for (int ni = 0; ni < 4; ++ni)
            bfr[ni] = *reinterpret_cast<const bf16x8*>(&Bl[rowB + ni * 512 + kq]);
        #pragma unroll
        for (int mi = 0; mi < 4; ++mi)
            #pragma unroll
            for (int ni = 0; ni < 4; ++ni)
                acc[mi][ni] = __builtin_amdgcn_mfma_f32_16x16x32_bf16(
                    af[mi], bfr[ni], acc[mi][ni], 0, 0, 0);
    }

    // epilogue: D[row=(l>>4)*4+v][col=l&15]; rows are consecutive spatial
    const float* dm = demod + n * OC;
    int ocol = l & 15, orow = (l >> 4) << 2;
    #pragma unroll
    for (int ni = 0; ni < 4; ++ni) {
        int oc = oc_base + wn * 64 + ni * 16 + ocol;
        float d = dm[oc];
        size_t obase = ((size_t)(n * OC + oc)) * SPATIAL + sp_base + wm * 64 + orow;
        if (isf) {
            float* op = (float*)out;
            #pragma unroll
            for (int mi = 0; mi < 4; ++mi) {
                f32x4 a = acc[mi][ni];
                f32x4 o = { a[0] * d, a[1] * d, a[2] * d, a[3] * d };
                *reinterpret_cast<f32x4*>(op + obase + mi * 16) = o;
            }
        } else {
            unsigned short* op = (unsigned short*)out;
            #pragma unroll
            for (int mi = 0; mi < 4; ++mi) {
                f32x4 a = acc[mi][ni];
                union { unsigned short u[4]; uint2 v; } pk;
                pk.u[0] = f2bu(a[0] * d); pk.u[1] = f2bu(a[1] * d);
                pk.u[2] = f2bu(a[2] * d); pk.u[3] = f2bu(a[3] * d);
                *reinterpret_cast<uint2*>(op + obase + mi * 16) = pk.v;
            }
        }
    }
}

extern "C" void kernel_launch(void* const* d_in, const int* in_sizes, int n_in,
                              void* d_out, int out_size, void* d_ws, size_t ws_size,
                              hipStream_t stream) {
    const void* x      = d_in[0];
    const void* style  = d_in[1];
    const void* weight = d_in[2];
    const void* mod_w  = d_in[3];
    const void* mod_b  = d_in[4];

    // ws layout (~35.5 MB)
    char* ws = (char*)d_ws;
    int*   flag  = (int*)(ws + 0);          // 1 KB slot
    float* scale = (float*)(ws + 1024);     // 16 KB
    float* demod = (float*)(ws + 17408);    // 16 KB
    float* wsq   = (float*)(ws + 33792);    // 256 KB
    bf16*  wt2   = (bf16*)(ws + 295936);    // 1.18 MB
    bf16*  xs    = (bf16*)(ws + 1475584);   // 35.7 MB padded NHWC

    k_detect<<<1, 64, 0, stream>>>(style, flag);
    k_scale<<<NB, 256, 0, stream>>>(style, mod_w, mod_b, flag, scale);
    k_wsq<<<OC, 256, 0, stream>>>(weight, flag, wsq);
    k_demod<<<NB, 256, 0, stream>>>(wsq, scale, demod);
    k_repack<<<9 * 256, 256, 0, stream>>>(weight, flag, wt2);
    int n4 = (NB * HWP * HWP * IC) / 8;
    k_zero<<<(n4 + 255) / 256, 256, 0, stream>>>((uint4*)xs, n4);
    k_xs<<<dim3(HW, NB), 256, 0, stream>>>(x, flag, scale, xs);
    k_conv<<<dim3(2, 512), 256, 0, stream>>>(xs, wt2, demod, flag, (void*)d_out);
}

// Round 3
// 283.595 us; speedup vs baseline: 1.1796x; 1.1796x over previous
//
#include <hip/hip_runtime.h>
#include <hip/hip_bf16.h>
#include <stdint.h>

// ModulatedConv2d: N=16, IC=OC=256, H=W=64, K=3, STYLE=512. fp32 in/out (confirmed
// by round-2 WRITE_SIZE=67MB passing validation). Compute: bf16 MFMA.
// out = demod[n,oc] * conv2d( x * (1+s)[n,ic], weight )   (StyleGAN2 identity)

#define NB  16
#define IC  256
#define OC  256
#define HW  64
#define HWP 66
#define SD  512
#define SPATIAL 4096

typedef __hip_bfloat16 bf16;
typedef __bf16 bf16x8 __attribute__((ext_vector_type(8)));
typedef float  f32x4  __attribute__((ext_vector_type(4)));
typedef uint32_t u32a3 __attribute__((address_space(3)));
typedef const uint32_t u32a1 __attribute__((address_space(1)));

static __device__ __forceinline__ unsigned short f2bu(float f) {
    bf16 h = __float2bfloat16(f);
    union { bf16 b; unsigned short u; } c; c.b = h; return c.u;
}
static __device__ __forceinline__ void gll16(const void* g, void* l) {
    __builtin_amdgcn_global_load_lds((u32a1*)g, (u32a3*)l, 16, 0, 0);
}

// --- K1: scale[n,ic] = 1 + style[n,:].mod_w[ic,:] + mod_b[ic]; wave/output --
__global__ void k_scale(const float* __restrict__ style, const float* __restrict__ mod_w,
                        const float* __restrict__ mod_b, float* __restrict__ scale) {
    int t = threadIdx.x, lane = t & 63;
    int w = blockIdx.x * 4 + (t >> 6);          // n*256+ic, 0..4095
    int n = w >> 8, ic = w & 255;
    const float4* mw4 = (const float4*)mod_w + (size_t)ic * 128 + lane * 2;
    const float4* st4 = (const float4*)style + (size_t)n * 128 + lane * 2;
    float4 a0 = mw4[0], a1 = mw4[1], s0 = st4[0], s1 = st4[1];
    float acc = a0.x*s0.x + a0.y*s0.y + a0.z*s0.z + a0.w*s0.w
              + a1.x*s1.x + a1.y*s1.y + a1.z*s1.z + a1.w*s1.w;
    #pragma unroll
    for (int off = 32; off > 0; off >>= 1) acc += __shfl_down(acc, off);
    if (lane == 0) scale[w] = acc + mod_b[ic] + 1.0f;
}

// --- K2: wsq[oc,ic] = sum_r w^2 ; wt2[r][oc][ic] = bf16(w) (fused) ----------
__global__ void k_prep_w(const float* __restrict__ weight, float* __restrict__ wsq,
                         bf16* __restrict__ wt2) {
    int tid = blockIdx.x * 256 + threadIdx.x;   // oc*256+ic
    const float* wp = weight + (size_t)tid * 9;
    float v[9], s = 0.f;
    #pragma unroll
    for (int r = 0; r < 9; ++r) { v[r] = wp[r]; s += v[r] * v[r]; }
    wsq[tid] = s;
    #pragma unroll
    for (int r = 0; r < 9; ++r) wt2[(r << 16) + tid] = __float2bfloat16(v[r]);
}

// --- K3: demod[n,oc] = rsqrt( sum_ic wsq[oc,ic]*scale[n,ic]^2 + eps ) -------
__global__ void k_demod(const float* __restrict__ wsq, const float* __restrict__ scale,
                        float* __restrict__ demod) {
    int t = threadIdx.x, lane = t & 63;
    int w = blockIdx.x * 4 + (t >> 6);          // n*256+oc
    int n = w >> 8, oc = w & 255;
    float4 q = ((const float4*)wsq)[(size_t)oc * 64 + lane];
    float4 s = ((const float4*)scale)[(size_t)n * 64 + lane];
    float acc = q.x*s.x*s.x + q.y*s.y*s.y + q.z*s.z*s.z + q.w*s.w*s.w;
    #pragma unroll
    for (int off = 32; off > 0; off >>= 1) acc += __shfl_down(acc, off);
    if (lane == 0) demod[w] = rsqrtf(acc + 1e-8f);
}

// --- K4: zero only the 1-px border of the padded NHWC buffer (2.1 MB) -------
__global__ void k_border(uint4* __restrict__ xs4) {
    int f = blockIdx.x * 256 + threadIdx.x;     // < 8448, valid < 8320
    int n = blockIdx.y;
    int u = f >> 5, q = f & 31;                 // unit = 256 elems = 32 uint4
    if (u >= 260) return;
    int rb;                                     // (y*66+x) cell index
    if      (u <  66) rb = u;                   // top row y=0
    else if (u < 132) rb = 65 * 66 + (u - 66);  // bottom row y=65
    else if (u < 196) rb = (u - 131) * 66;      // left col, y=1..64
    else              rb = (u - 195) * 66 + 65; // right col, y=1..64
    xs4[(size_t)n * 139392 + rb * 32 + q] = make_uint4(0u, 0u, 0u, 0u);
}

// --- K5: xs[n][1+y][1+x][ic] = bf16( x[n,ic,y,x] * scale[n,ic] ) ------------
__global__ void k_xs(const float* __restrict__ x, const float* __restrict__ scale,
                     bf16* __restrict__ xs) {
    __shared__ unsigned short tile[HW * 264];   // [sp][ic], row padded to 264
    int y = blockIdx.x, n = blockIdx.y, t = threadIdx.x;
    const float* sc = scale + n * IC;
    const float4* xp4 = (const float4*)(x + ((size_t)n * IC) * SPATIAL + (size_t)y * HW);
    #pragma unroll
    for (int i = 0; i < 16; ++i) {
        int fid = i * 256 + t;
        int ic = fid >> 4, f4 = fid & 15;       // 16 float4 per 64-wide row
        float4 v = xp4[(size_t)ic * 1024 + f4];
        float s = sc[ic];
        int sp = f4 * 4;
        tile[(sp + 0) * 264 + ic] = f2bu(v.x * s);
        tile[(sp + 1) * 264 + ic] = f2bu(v.y * s);
        tile[(sp + 2) * 264 + ic] = f2bu(v.z * s);
        tile[(sp + 3) * 264 + ic] = f2bu(v.w * s);
    }
    __syncthreads();
    uint4* dst4 = (uint4*)(xs + (((size_t)n * HWP + (y + 1)) * HWP + 1) * IC);
    #pragma unroll
    for (int j = 0; j < 8; ++j) {
        int uid = j * 256 + t;
        int sp = uid >> 5, g = uid & 31;        // 32 uint4 per spatial position
        dst4[sp * 32 + g] = *(const uint4*)&tile[sp * 264 + g * 8];
    }
}

// --- K6: implicit-GEMM conv. 128 spatial x 128 oc, BK=64, A via swizzled ----
// gll16 (conflict-free LDS reads), B direct from L2 into registers.
__global__ __launch_bounds__(256, 4)
void k_conv(const bf16* __restrict__ xs, const bf16* __restrict__ wt2,
            const float* __restrict__ demod, float* __restrict__ out) {
    __shared__ unsigned short Al[128 * 64];     // 16 KB, [row][k] with XOR-swizzled segs
    int t = threadIdx.x, l = t & 63, w = t >> 6;
    int wm = w & 1, wn = w >> 1;
    int bid = blockIdx.x;
    int work = ((bid & 7) << 7) | (bid >> 3);   // XCD-contiguous: xcd*128 + slot
    int bn = work & 1, st = work >> 1;          // oc tile, spatial tile
    int n = st >> 5;
    int sp_base = (st & 31) << 7;               // 128 positions = 2 image rows
    int oc_base = bn << 7;

    // A staging: wave w stages rows [w*32, w*32+32); lane l -> row w*32+(l>>3),
    // LDS seg l&7; fetches GLOBAL k-seg (l&7)^(l>>3)  (XOR swizzle).
    int lrow = l >> 3;
    int lseg = (l & 7) ^ lrow;
    int sp0 = sp_base + w * 32 + lrow;
    const bf16* gA0 = xs + (((size_t)n * HWP + (sp0 >> 6)) * HWP + (sp0 & 63)) * IC + lseg * 8;
    char* Ab = (char*)Al + w * 4096;            // +i*1024 per 8-row group

    // B direct: lane l covers oc = base + (l&15), k-eights at (l>>4)*8
    const bf16* gBd = wt2 + (size_t)(oc_base + wn * 64 + (l & 15)) * IC + (l >> 4) * 8;

    f32x4 acc[4][4];
    #pragma unroll
    for (int i = 0; i < 4; ++i)
        #pragma unroll
        for (int j = 0; j < 4; ++j) acc[i][j] = (f32x4){0.f, 0.f, 0.f, 0.f};

    int rowA = wm * 64 + (l & 15);
    int q0 = l >> 4, xk = l & 7;

    for (int ch = 0; ch < 36; ++ch) {
        int r = ch >> 2;                        // shift 0..8
        int ic0 = (ch & 3) << 6;                // 64-ic chunk
        int ky = r / 3, kx = r - ky * 3;
        int aoff = (ky * HWP + kx) * IC + ic0;  // wave-uniform
        int boff = (r << 16) + ic0;
        __syncthreads();                        // prev reads done before overwrite
        #pragma unroll
        for (int i = 0; i < 4; ++i)
            gll16(gA0 + aoff + i * 2048, Ab + i * 1024);
        __syncthreads();
        #pragma unroll
        for (int kk = 0; kk < 2; ++kk) {
            bf16x8 bfr[4], af[4];
            #pragma unroll
            for (int ni = 0; ni < 4; ++ni)
                bfr[ni] = *reinterpret_cast<const bf16x8*>(
                    gBd + boff + kk * 32 + ni * 16 * IC);
            #pragma unroll
            for (int mi = 0; mi < 4; ++mi)
                af[mi] = *reinterpret_cast<const bf16x8*>(
                    &Al[(rowA + mi * 16) * 64 + ((((kk << 2) + q0) ^ xk) << 3)]);
            #pragma unroll
            for (int mi = 0; mi < 4; ++mi)
                #pragma unroll
                for (int ni = 0; ni < 4; ++ni)
                    acc[mi][ni] = __builtin_amdgcn_mfma_f32_16x16x32_bf16(
                        af[mi], bfr[ni], acc[mi][ni], 0, 0, 0);
        }
    }

    // epilogue: D[row=(l>>4)*4+v][col=l&15], rows = consecutive spatial -> 16B stores
    const float* dm = demod + n * OC;
    int ocol = l & 15, orow = (l >> 4) << 2;
    #pragma unroll
    for (int ni = 0; ni < 4; ++ni) {
        int oc = oc_base + wn * 64 + ni * 16 + ocol;
        float d = dm[oc];
        size_t ob = ((size_t)(n * OC + oc)) * SPATIAL + sp_base + wm * 64 + orow;
        #pragma unroll
        for (int mi = 0; mi < 4; ++mi) {
            f32x4 a = acc[mi][ni];
            f32x4 o = { a[0] * d, a[1] * d, a[2] * d, a[3] * d };
            *reinterpret_cast<f32x4*>(out + ob + mi * 16) = o;
        }
    }
}

extern "C" void kernel_launch(void* const* d_in, const int* in_sizes, int n_in,
                              void* d_out, int out_size, void* d_ws, size_t ws_size,
                              hipStream_t stream) {
    const float* x      = (const float*)d_in[0];
    const float* style  = (const float*)d_in[1];
    const float* weight = (const float*)d_in[2];
    const float* mod_w  = (const float*)d_in[3];
    const float* mod_b  = (const float*)d_in[4];
    float* out = (float*)d_out;

    char* ws = (char*)d_ws;                  // ~37.2 MB
    float* scale = (float*)(ws + 0);         // 16 KB
    float* demod = (float*)(ws + 16384);     // 16 KB
    float* wsq   = (float*)(ws + 32768);     // 256 KB
    bf16*  wt2   = (bf16*)(ws + 294912);     // 1.18 MB [r][oc][ic]
    bf16*  xs    = (bf16*)(ws + 1474560);    // 35.7 MB padded NHWC

    k_scale<<<1024, 256, 0, stream>>>(style, mod_w, mod_b, scale);
    k_prep_w<<<256, 256, 0, stream>>>(weight, wsq, wt2);
    k_border<<<dim3(33, NB), 256, 0, stream>>>((uint4*)xs);
    k_demod<<<1024, 256, 0, stream>>>(wsq, scale, demod);
    k_xs<<<dim3(HW, NB), 256, 0, stream>>>(x, scale, xs);
    k_conv<<<1024, 256, 0, stream>>>(xs, wt2, demod, out);
}

// Round 4
// 201.989 us; speedup vs baseline: 1.6561x; 1.4040x over previous
//
#include <hip/hip_runtime.h>
#include <hip/hip_bf16.h>
#include <stdint.h>

// ModulatedConv2d: N=16, IC=OC=256, H=W=64, K=3, STYLE=512. fp32 in/out.
// out = demod[n,oc] * conv2d( x * (1+s)[n,ic], weight )   (StyleGAN2 identity)
// R4: conv = all-LDS staging (A+B) with XOR-swizzled conflict-free layout, BK=64;
//     prep fused into 2 kernels (launch-gap was ~10us x 6).

#define NB  16
#define IC  256
#define OC  256
#define HW  64
#define HWP 66
#define SD  512
#define SPATIAL 4096

typedef __hip_bfloat16 bf16;
typedef __bf16 bf16x8 __attribute__((ext_vector_type(8)));
typedef float  f32x4  __attribute__((ext_vector_type(4)));
typedef uint32_t u32a3 __attribute__((address_space(3)));
typedef const uint32_t u32a1 __attribute__((address_space(1)));

static __device__ __forceinline__ unsigned short f2bu(float f) {
    bf16 h = __float2bfloat16(f);
    union { bf16 b; unsigned short u; } c; c.b = h; return c.u;
}
static __device__ __forceinline__ void gll16(const void* g, void* l) {
    __builtin_amdgcn_global_load_lds((u32a1*)g, (u32a3*)l, 16, 0, 0);
}

// --- P1: fused prep. blocks [0,256): wt2/wsq; [256,784): border; [784,1808): scale
__global__ __launch_bounds__(256)
void k_prep1(const float* __restrict__ weight, const float* __restrict__ style,
             const float* __restrict__ mod_w, const float* __restrict__ mod_b,
             float* __restrict__ wsq, bf16* __restrict__ wt2,
             uint4* __restrict__ xs4, float* __restrict__ scale) {
    int b = blockIdx.x, t = threadIdx.x;
    if (b < 256) {
        // wsq[oc,ic] = sum_r w^2 ; wt2[r][oc][ic] = bf16(w)
        int tid = b * 256 + t;
        const float* wp = weight + (size_t)tid * 9;
        float v[9], s = 0.f;
        #pragma unroll
        for (int r = 0; r < 9; ++r) { v[r] = wp[r]; s += v[r] * v[r]; }
        wsq[tid] = s;
        #pragma unroll
        for (int r = 0; r < 9; ++r) wt2[(r << 16) + tid] = __float2bfloat16(v[r]);
    } else if (b < 784) {
        // zero 1-px border ring of padded NHWC xs
        int idx = b - 256;
        int n = idx / 33, bx = idx - n * 33;
        int f = bx * 256 + t;
        int u = f >> 5, q = f & 31;
        if (u >= 260) return;
        int rb;
        if      (u <  66) rb = u;
        else if (u < 132) rb = 65 * 66 + (u - 66);
        else if (u < 196) rb = (u - 131) * 66;
        else              rb = (u - 195) * 66 + 65;
        xs4[(size_t)n * 139392 + rb * 32 + q] = make_uint4(0u, 0u, 0u, 0u);
    } else {
        // scale[n,ic] = 1 + style[n,:].mod_w[ic,:] + mod_b[ic]; one wave/output
        int lane = t & 63;
        int w = (b - 784) * 4 + (t >> 6);
        int n = w >> 8, ic = w & 255;
        const float4* mw4 = (const float4*)mod_w + (size_t)ic * 128 + lane * 2;
        const float4* st4 = (const float4*)style + (size_t)n * 128 + lane * 2;
        float4 a0 = mw4[0], a1 = mw4[1], s0 = st4[0], s1 = st4[1];
        float acc = a0.x*s0.x + a0.y*s0.y + a0.z*s0.z + a0.w*s0.w
                  + a1.x*s1.x + a1.y*s1.y + a1.z*s1.z + a1.w*s1.w;
        #pragma unroll
        for (int off = 32; off > 0; off >>= 1) acc += __shfl_down(acc, off);
        if (lane == 0) scale[w] = acc + mod_b[ic] + 1.0f;
    }
}

// --- P2: blocks [0,1024): xs modulate+transpose; [1024,1040): demod ---------
__global__ __launch_bounds__(256)
void k_prep2(const float* __restrict__ x, const float* __restrict__ scale,
             const float* __restrict__ wsq, bf16* __restrict__ xs,
             float* __restrict__ demod) {
    __shared__ unsigned short tile[HW * 264];   // also reused by demod path
    int b = blockIdx.x, t = threadIdx.x;
    if (b < 1024) {
        int y = b & 63, n = b >> 6;
        const float* sc = scale + n * IC;
        const float4* xp4 = (const float4*)(x + ((size_t)n * IC) * SPATIAL + (size_t)y * HW);
        #pragma unroll
        for (int i = 0; i < 16; ++i) {
            int fid = i * 256 + t;
            int ic = fid >> 4, f4 = fid & 15;
            float4 v = xp4[(size_t)ic * 1024 + f4];
            float s = sc[ic];
            int sp = f4 * 4;
            tile[(sp + 0) * 264 + ic] = f2bu(v.x * s);
            tile[(sp + 1) * 264 + ic] = f2bu(v.y * s);
            tile[(sp + 2) * 264 + ic] = f2bu(v.z * s);
            tile[(sp + 3) * 264 + ic] = f2bu(v.w * s);
        }
        __syncthreads();
        uint4* dst4 = (uint4*)(xs + (((size_t)n * HWP + (y + 1)) * HWP + 1) * IC);
        #pragma unroll
        for (int j = 0; j < 8; ++j) {
            int uid = j * 256 + t;
            int sp = uid >> 5, g = uid & 31;
            dst4[sp * 32 + g] = *(const uint4*)&tile[sp * 264 + g * 8];
        }
    } else {
        // demod[n,oc] = rsqrt( sum_ic wsq[oc,ic]*scale[n,ic]^2 + eps )
        int n = b - 1024, oc = t;
        float* sc = (float*)tile;
        sc[t] = scale[n * IC + t];
        __syncthreads();
        const float4* wp4 = (const float4*)(wsq + (size_t)oc * IC);
        const float4* sc4 = (const float4*)sc;
        float acc = 0.f;
        #pragma unroll 8
        for (int i = 0; i < 64; ++i) {
            float4 q = wp4[i], s = sc4[i];
            acc += q.x*s.x*s.x + q.y*s.y*s.y + q.z*s.z*s.z + q.w*s.w*s.w;
        }
        demod[n * OC + oc] = rsqrtf(acc + 1e-8f);
    }
}

// --- K6: implicit-GEMM conv. 128 spatial x 128 oc, BK=64. A and B staged ----
// via gll16 into XOR-swizzled LDS (row stride 128B; seg s holds global seg
// s^(row&7)) -> conflict-free ds_read_b128 (verified: 0 conflicts in R3).
__global__ __launch_bounds__(256, 4)
void k_conv(const bf16* __restrict__ xs, const bf16* __restrict__ wt2,
            const float* __restrict__ demod, float* __restrict__ out) {
    __shared__ unsigned short Al[128 * 64];     // 16 KB
    __shared__ unsigned short Bl[128 * 64];     // 16 KB
    int t = threadIdx.x, l = t & 63, w = t >> 6;
    int wm = w & 1, wn = w >> 1;
    int bid = blockIdx.x;
    int work = ((bid & 7) << 7) | (bid >> 3);   // XCD-contiguous: xcd*128 + slot
    int bn = work & 1, st = work >> 1;
    int n = st >> 5;
    int sp_base = (st & 31) << 7;               // 128 positions = 2 image rows
    int oc_base = bn << 7;

    // staging: wave w -> rows [w*32, w*32+32); lane l -> row w*32+(l>>3)+8i,
    // fetch global k-seg (l&7)^(l>>3), land at LDS seg (l&7).
    int lrow = l >> 3;
    int lseg = (l & 7) ^ lrow;
    int sp0 = sp_base + w * 32 + lrow;
    const bf16* gA0 = xs + (((size_t)n * HWP + (sp0 >> 6)) * HWP + (sp0 & 63)) * IC + lseg * 8;
    const bf16* gB0 = wt2 + (size_t)(oc_base + w * 32 + lrow) * IC + lseg * 8;
    char* Ab = (char*)Al + w * 4096;
    char* Bb = (char*)Bl + w * 4096;

    f32x4 acc[4][4];
    #pragma unroll
    for (int i = 0; i < 4; ++i)
        #pragma unroll
        for (int j = 0; j < 4; ++j) acc[i][j] = (f32x4){0.f, 0.f, 0.f, 0.f};

    int rAbase = (wm * 64 + (l & 15)) * 64;     // element offsets, row stride 64
    int rBbase = (wn * 64 + (l & 15)) * 64;
    int q0 = l >> 4, xk = l & 7;

    for (int ch = 0; ch < 36; ++ch) {
        int r = ch >> 2;                        // shift 0..8
        int ic0 = (ch & 3) << 6;                // 64-ic chunk
        int ky = r / 3, kx = r - ky * 3;
        int aoff = (ky * HWP + kx) * IC + ic0;  // wave-uniform
        int boff = (r << 16) + ic0;
        __syncthreads();
        #pragma unroll
        for (int i = 0; i < 4; ++i)
            gll16(gA0 + aoff + i * 2048, Ab + i * 1024);
        #pragma unroll
        for (int i = 0; i < 4; ++i)
            gll16(gB0 + boff + i * 2048, Bb + i * 1024);
        __syncthreads();
        #pragma unroll
        for (int kk = 0; kk < 2; ++kk) {
            int ks = (((kk << 2) + q0) ^ xk) << 3;
            bf16x8 af[4], bfr[4];
            #pragma unroll
            for (int mi = 0; mi < 4; ++mi)
                af[mi] = *reinterpret_cast<const bf16x8*>(&Al[rAbase + mi * 1024 + ks]);
            #pragma unroll
            for (int ni = 0; ni < 4; ++ni)
                bfr[ni] = *reinterpret_cast<const bf16x8*>(&Bl[rBbase + ni * 1024 + ks]);
            #pragma unroll
            for (int mi = 0; mi < 4; ++mi)
                #pragma unroll
                for (int ni = 0; ni < 4; ++ni)
                    acc[mi][ni] = __builtin_amdgcn_mfma_f32_16x16x32_bf16(
                        af[mi], bfr[ni], acc[mi][ni], 0, 0, 0);
        }
    }

    // epilogue: D[row=(l>>4)*4+v][col=l&15]; rows = consecutive spatial -> 16B stores
    const float* dm = demod + n * OC;
    int ocol = l & 15, orow = (l >> 4) << 2;
    #pragma unroll
    for (int ni = 0; ni < 4; ++ni) {
        int oc = oc_base + wn * 64 + ni * 16 + ocol;
        float d = dm[oc];
        size_t ob = ((size_t)(n * OC + oc)) * SPATIAL + sp_base + wm * 64 + orow;
        #pragma unroll
        for (int mi = 0; mi < 4; ++mi) {
            f32x4 a = acc[mi][ni];
            f32x4 o = { a[0] * d, a[1] * d, a[2] * d, a[3] * d };
            *reinterpret_cast<f32x4*>(out + ob + mi * 16) = o;
        }
    }
}

extern "C" void kernel_launch(void* const* d_in, const int* in_sizes, int n_in,
                              void* d_out, int out_size, void* d_ws, size_t ws_size,
                              hipStream_t stream) {
    const float* x      = (const float*)d_in[0];
    const float* style  = (const float*)d_in[1];
    const float* weight = (const float*)d_in[2];
    const float* mod_w  = (const float*)d_in[3];
    const float* mod_b  = (const float*)d_in[4];
    float* out = (float*)d_out;

    char* ws = (char*)d_ws;                  // ~37.2 MB
    float* scale = (float*)(ws + 0);         // 16 KB
    float* demod = (float*)(ws + 16384);     // 16 KB
    float* wsq   = (float*)(ws + 32768);     // 256 KB
    bf16*  wt2   = (bf16*)(ws + 294912);     // 1.18 MB [r][oc][ic]
    bf16*  xs    = (bf16*)(ws + 1474560);    // 35.7 MB padded NHWC

    k_prep1<<<1808, 256, 0, stream>>>(weight, style, mod_w, mod_b,
                                      wsq, wt2, (uint4*)xs, scale);
    k_prep2<<<1040, 256, 0, stream>>>(x, scale, wsq, xs, demod);
    k_conv<<<1024, 256, 0, stream>>>(xs, wt2, demod, out);
}